// Round 10
// baseline (20956.352 us; speedup 1.0000x reference)
//
#include <hip/hip_runtime.h>

typedef unsigned int u32;
typedef unsigned long long u64;
typedef float f32x2 __attribute__((ext_vector_type(2)));

#define NPB 8192
#define BCL 4
#define MS 2048
#define KN 64
#define OFF_POS   (BCL * MS * 128)            // element offsets into d_out (f32)
#define OFF_BATCH (OFF_POS + BCL * MS * 3)
#define WS_PTS_OFF (BCL * MS + BCL * MS * KN) // int offset of pts4 in ws

__device__ inline u64 umax64(u64 a, u64 b) { return a < b ? b : a; }
__device__ inline u32 umax32(u32 a, u32 b) { return a < b ? b : a; }

// key: [63:32]=d2 bits, [31:19]=~origidx (13b), [18:6]=sorted storage pos.
// u64 max == lexicographic (d2, ~orig) - np.argmax first-index tie semantics;
// storage pos rides along (unique (d2,orig) decides before pos is compared).
__device__ inline u64 mkkey(float d2, u32 orig, u32 q) {
  return ((u64)__float_as_uint(d2) << 32) |
         ((u64)((~orig) & 0x1FFFu) << 19) | ((u64)q << 6);
}

// packed f32 ops: IEEE-identical per half to v_add_f32 / v_mul_f32 -> bit-exact
__device__ inline f32x2 pk_add(f32x2 a, f32x2 b) {
  f32x2 d;
  asm("v_pk_add_f32 %0, %1, %2" : "=v"(d) : "v"(a), "v"(b));
  return d;
}
__device__ inline f32x2 pk_mul(f32x2 a, f32x2 b) {
  f32x2 d;
  asm("v_pk_mul_f32 %0, %1, %2" : "=v"(d) : "v"(a), "v"(b));
  return d;
}

// wave64 max via DPP (VALU forwarding, no LDS round-trips).
__device__ inline u32 wave_max_u32(u32 v) {
  v = umax32(v, (u32)__builtin_amdgcn_update_dpp(0, (int)v, 0x111, 0xf, 0xf, false));
  v = umax32(v, (u32)__builtin_amdgcn_update_dpp(0, (int)v, 0x112, 0xf, 0xf, false));
  v = umax32(v, (u32)__builtin_amdgcn_update_dpp(0, (int)v, 0x114, 0xf, 0xf, false));
  v = umax32(v, (u32)__builtin_amdgcn_update_dpp(0, (int)v, 0x118, 0xf, 0xf, false));
  v = umax32(v, (u32)__builtin_amdgcn_update_dpp(0, (int)v, 0x142, 0xa, 0xf, false));
  v = umax32(v, (u32)__builtin_amdgcn_update_dpp(0, (int)v, 0x143, 0xc, 0xf, false));
  return (u32)__builtin_amdgcn_readlane((int)v, 63);
}
// two-phase DPP reduce == lexicographic u64 max over the wave
__device__ inline u64 wave_max_key(u64 lkey) {
  u32 hi = (u32)(lkey >> 32), lo32v = (u32)lkey;
  u32 m = wave_max_u32(hi);
  u32 c = wave_max_u32(hi == m ? lo32v : 0u);
  return ((u64)m << 32) | c;
}

__device__ inline u32 part1by2(u32 x) {   // spread 10 bits -> every 3rd bit
  x &= 0x3ffu;
  x = (x | (x << 16)) & 0x030000FFu;
  x = (x | (x << 8))  & 0x0300F00Fu;
  x = (x | (x << 4))  & 0x030C30C3u;
  x = (x | (x << 2))  & 0x09249249u;
  return x;
}

// ---------------------------------------------------------------------------
// Kernel 1a: Morton sort (R6-proven), writes sorted float4{x,y,z,origidx}
// to workspace. One 1024-thread block per cloud, 64 KB dynamic LDS.
// ---------------------------------------------------------------------------
__global__ __launch_bounds__(1024) void sort_kernel(
    const float* __restrict__ pos, float4* __restrict__ pts) {
  extern __shared__ u64 smem[];
  int b = blockIdx.x, t = threadIdx.x;
  const float* pb = pos + (size_t)b * NPB * 3;
  for (int i = t; i < NPB; i += 1024) {
    float xx = pb[i * 3], yy = pb[i * 3 + 1], zz = pb[i * 3 + 2];
    u32 xi = (u32)fminf(fmaxf(xx * 1024.0f, 0.0f), 1023.0f);
    u32 yi = (u32)fminf(fmaxf(yy * 1024.0f, 0.0f), 1023.0f);
    u32 zi = (u32)fminf(fmaxf(zz * 1024.0f, 0.0f), 1023.0f);
    u32 m = (part1by2(zi) << 2) | (part1by2(yi) << 1) | part1by2(xi);
    smem[i] = ((u64)m << 13) | (u32)i;
  }
  for (int k = 2; k <= NPB; k <<= 1) {
    for (int j = k >> 1; j > 0; j >>= 1) {
      __syncthreads();
      for (int i = t; i < NPB; i += 1024) {
        int ix = i ^ j;
        if (ix > i) {
          u64 a = smem[i], c = smem[ix];
          bool up = ((i & k) == 0);
          if ((a > c) == up) { smem[i] = c; smem[ix] = a; }
        }
      }
    }
  }
  __syncthreads();
  for (int p = t; p < NPB; p += 1024) {
    int oi = (int)(smem[p] & 0x1FFFu);
    pts[(size_t)b * NPB + p] =
        make_float4(pb[oi * 3], pb[oi * 3 + 1], pb[oi * 3 + 2],
                    __uint_as_float((u32)oi));
  }
}

// ---------------------------------------------------------------------------
// Kernel 1b: FPS loop, ONE WAVE per cloud (64 thr), 128 pts/lane in 4
// sub-blobs of 32 (Morton-contiguous). NO barriers, NO LDS in the loop:
// DPP reduce -> uniform L2 winner fetch -> per-sub-blob bbox skip ->
// exec-masked exact update (re-reads sub-blob from L2-hot ws, umax tree).
// Bit-exact: same per-point pk arithmetic, np tie semantics via key layout,
// skips provable no-ops (64-eps margin vs <=8-eps slack). absmax 0.0 R3-R9.
// ---------------------------------------------------------------------------
__global__ __launch_bounds__(64, 1) void fps_loop_kernel(
    const float* __restrict__ pos, const float4* __restrict__ pts,
    int* __restrict__ samp, float* __restrict__ out) {
  int b = blockIdx.x, l = threadIdx.x;
  const float4* cp = pts + (size_t)b * NPB;       // cloud base (sorted)
  const float4* myp = cp + l * 128;               // my 128 points
  float* pos_out = out + OFF_POS + (size_t)b * MS * 3;
  float* batch_out = out + OFF_BATCH + (size_t)b * MS;

  float cx = pos[(size_t)b * NPB * 3];            // original point 0
  float cy = pos[(size_t)b * NPB * 3 + 1];
  float cz = pos[(size_t)b * NPB * 3 + 2];
  if (l == 0) {
    samp[b * MS] = 0;
    pos_out[0] = cx; pos_out[1] = cy; pos_out[2] = cz;
  }

  // ---- init: mind vs point0, 4 sub-bboxes, 4 sub-keys ----
  f32x2 mind[64];
  u64 skey[4];
  float bxl[4], bxh[4], byl[4], byh[4], bzl[4], bzh[4];
  {
    f32x2 mcx = f32x2{-cx, -cx}, mcy = f32x2{-cy, -cy}, mcz = f32x2{-cz, -cz};
    #pragma unroll
    for (int s = 0; s < 4; ++s) {
      float xl = 1e30f, xh = -1e30f, yl = 1e30f, yh = -1e30f, zl = 1e30f, zh = -1e30f;
      u64 acc = 0;
      #pragma unroll
      for (int j2 = 0; j2 < 16; ++j2) {
        int j = s * 16 + j2;
        float4 A = myp[2 * j], B = myp[2 * j + 1];
        xl = fminf(xl, fminf(A.x, B.x)); xh = fmaxf(xh, fmaxf(A.x, B.x));
        yl = fminf(yl, fminf(A.y, B.y)); yh = fmaxf(yh, fmaxf(A.y, B.y));
        zl = fminf(zl, fminf(A.z, B.z)); zh = fmaxf(zh, fmaxf(A.z, B.z));
        f32x2 X = f32x2{A.x, B.x}, Y = f32x2{A.y, B.y}, Z = f32x2{A.z, B.z};
        f32x2 dx = pk_add(X, mcx), dy = pk_add(Y, mcy), dz = pk_add(Z, mcz);
        mind[j] = pk_add(pk_add(pk_mul(dx, dx), pk_mul(dy, dy)), pk_mul(dz, dz));
        u64 kA = mkkey(mind[j].x, __float_as_uint(A.w), (u32)(l * 128 + 2 * j));
        u64 kB = mkkey(mind[j].y, __float_as_uint(B.w), (u32)(l * 128 + 2 * j + 1));
        acc = umax64(acc, umax64(kA, kB));
      }
      bxl[s] = xl; bxh[s] = xh; byl[s] = yl; byh[s] = yh; bzl[s] = zl; bzh[s] = zh;
      skey[s] = acc;
    }
  }
  u64 lkey = umax64(umax64(skey[0], skey[1]), umax64(skey[2], skey[3]));

  // ---- sequential loop: no barriers, wave-synchronous ----
  for (int it = 1; it < MS; ++it) {
    u64 wkey = wave_max_key(lkey);
    u32 q = (u32)(wkey >> 6) & 0x1FFFu;
    int win = (int)((~(u32)(wkey >> 19)) & 0x1FFFu);
    float4 W = cp[q];                    // uniform L2 read (winner coords)
    if (l == 0) {
      samp[b * MS + it] = win;
      pos_out[it * 3] = W.x; pos_out[it * 3 + 1] = W.y; pos_out[it * 3 + 2] = W.z;
    }
    float ncx = W.x, ncy = W.y, ncz = W.z;
    f32x2 mcx = f32x2{-ncx, -ncx}, mcy = f32x2{-ncy, -ncy}, mcz = f32x2{-ncz, -ncz};
    #pragma unroll
    for (int s = 0; s < 4; ++s) {
      // conservative bbox skip test (bit-exact: only skips provable no-ops)
      float lmax = __uint_as_float((u32)(skey[s] >> 32));
      float ax = fmaxf(fmaxf(__fsub_rn(bxl[s], ncx), __fsub_rn(ncx, bxh[s])), 0.0f);
      float ay = fmaxf(fmaxf(__fsub_rn(byl[s], ncy), __fsub_rn(ncy, byh[s])), 0.0f);
      float az = fmaxf(fmaxf(__fsub_rn(bzl[s], ncz), __fsub_rn(ncz, bzh[s])), 0.0f);
      float lb2 = (ax * ax + ay * ay + az * az) * 0.9999961853f;  // *(1-2^-18)
      if (lb2 <= lmax) {                 // exec-masked exact update
        u64 acc = 0;
        #pragma unroll
        for (int j2 = 0; j2 < 16; ++j2) {
          int j = s * 16 + j2;
          float4 A = myp[2 * j], B = myp[2 * j + 1];
          f32x2 X = f32x2{A.x, B.x}, Y = f32x2{A.y, B.y}, Z = f32x2{A.z, B.z};
          f32x2 dx = pk_add(X, mcx), dy = pk_add(Y, mcy), dz = pk_add(Z, mcz);
          f32x2 d2 = pk_add(pk_add(pk_mul(dx, dx), pk_mul(dy, dy)), pk_mul(dz, dz));
          mind[j].x = fminf(mind[j].x, d2.x);
          mind[j].y = fminf(mind[j].y, d2.y);
          u64 kA = mkkey(mind[j].x, __float_as_uint(A.w), (u32)(l * 128 + 2 * j));
          u64 kB = mkkey(mind[j].y, __float_as_uint(B.w), (u32)(l * 128 + 2 * j + 1));
          acc = umax64(acc, umax64(kA, kB));
        }
        skey[s] = acc;
      }
    }
    lkey = umax64(umax64(skey[0], skey[1]), umax64(skey[2], skey[3]));
  }
  for (int m = l; m < MS; m += 64) batch_out[m] = (float)b;
}

// ---------------------------------------------------------------------------
// Kernel 2: radius ball + K-nearest-in-ball (lax.top_k semantics). FROZEN.
// ---------------------------------------------------------------------------
__global__ __launch_bounds__(256) void nbr_kernel(
    const float* __restrict__ pos, const int* __restrict__ samp,
    int* __restrict__ nbr) {
  const float R2CUT = (float)(0.2 * 0.2);   // 0x3D23D70A
  int c = blockIdx.x, b = c >> 11, t = threadIdx.x;
  const float* pb = pos + (size_t)b * NPB * 3;
  int s = samp[c] & (NPB - 1);
  float cx = pb[s * 3], cy = pb[s * 3 + 1], cz = pb[s * 3 + 2];
  __shared__ u64 cand[512];
  __shared__ int cnt;
  if (t == 0) cnt = 0;
  __syncthreads();
  for (int j = t; j < NPB; j += 256) {
    float dx = __fsub_rn(pb[j * 3], cx);
    float dy = __fsub_rn(pb[j * 3 + 1], cy);
    float dz = __fsub_rn(pb[j * 3 + 2], cz);
    float d2 = __fadd_rn(__fadd_rn(__fmul_rn(dx, dx), __fmul_rn(dy, dy)), __fmul_rn(dz, dz));
    if (d2 <= R2CUT) {
      int sl = atomicAdd(&cnt, 1);
      if (sl < 512) cand[sl] = ((u64)__float_as_uint(d2) << 32) | (u32)j;
    }
  }
  __syncthreads();
  int n = cnt; if (n > 512) n = 512;
  for (int i = t; i < 512; i += 256) if (i >= n) cand[i] = ~0ull;
  __syncthreads();
  for (int k = 2; k <= 512; k <<= 1) {
    for (int j = k >> 1; j > 0; j >>= 1) {
      for (int i = t; i < 512; i += 256) {
        int ix = i ^ j;
        if (ix > i) {
          u64 a = cand[i], bb = cand[ix];
          bool up = ((i & k) == 0);
          if ((a > bb) == up) { cand[i] = bb; cand[ix] = a; }
        }
      }
      __syncthreads();
    }
  }
  if (t < KN) nbr[(size_t)c * KN + t] = (t < n) ? (int)(cand[t] & 0xffffffffu) : -1;
}

// ---------------------------------------------------------------------------
// Kernel 3: gather -> f32 VALU MLP -> masked max-pool. FROZEN (absmax 0.0).
// ---------------------------------------------------------------------------
__global__ __launch_bounds__(256) void mlp_kernel(
    const float* __restrict__ x, const float* __restrict__ pos,
    const int* __restrict__ samp, const int* __restrict__ nbr,
    const float* __restrict__ W1, const float* __restrict__ b1,
    const float* __restrict__ W2, const float* __restrict__ b2,
    const float* __restrict__ W3, const float* __restrict__ b3,
    float* __restrict__ out) {
  int c = blockIdx.x, b = c >> 11, t = threadIdx.x;

  __shared__ float s_feat[64][68];
  __shared__ float s_h[64][68];
  __shared__ float s_w[68][64];
  __shared__ float s_mask[64];
  __shared__ float s_red[4][64];

  const int* nb = nbr + (size_t)c * KN;

  {
    int r = t >> 2, q = t & 3;
    int j = nb[r];
    bool valid = (j >= 0 && j < NPB);
    size_t jj = valid ? (size_t)j : 0;
    const float4* xp = (const float4*)(x + ((size_t)b * NPB + jj) * 64 + q * 16);
    float4 v[4];
    for (int i = 0; i < 4; ++i) v[i] = xp[i];
    for (int i = 0; i < 4; ++i) {
      s_feat[r][q * 16 + i * 4 + 0] = valid ? v[i].x : 0.0f;
      s_feat[r][q * 16 + i * 4 + 1] = valid ? v[i].y : 0.0f;
      s_feat[r][q * 16 + i * 4 + 2] = valid ? v[i].z : 0.0f;
      s_feat[r][q * 16 + i * 4 + 3] = valid ? v[i].w : 0.0f;
    }
  }
  if (t < 64) {
    int r = t;
    int j = nb[r];
    bool valid = (j >= 0 && j < NPB);
    s_mask[r] = valid ? 0.0f : -__builtin_inff();
    int s = samp[c] & (NPB - 1);
    size_t jj = valid ? (size_t)j : (size_t)s;
    for (int d = 0; d < 3; ++d) {
      float pj = pos[((size_t)b * NPB + jj) * 3 + d];
      float pc = pos[((size_t)b * NPB + s) * 3 + d];
      s_feat[r][64 + d] = __fsub_rn(pj, pc);
    }
  }
  for (int idx = t; idx < 67 * 64; idx += 256)
    s_w[idx >> 6][idx & 63] = W1[idx];
  __syncthreads();

  {
    int r = t >> 2, n0 = (t & 3) * 16;
    float acc[16];
    for (int j = 0; j < 16; ++j) acc[j] = b1[n0 + j];
    for (int k = 0; k < 67; ++k) {
      float f = s_feat[r][k];
      for (int j = 0; j < 16; ++j) acc[j] += f * s_w[k][n0 + j];
    }
    __syncthreads();
    for (int j = 0; j < 16; ++j) s_h[r][n0 + j] = fmaxf(acc[j], 0.0f);
  }
  for (int idx = t; idx < 64 * 64; idx += 256)
    s_w[idx >> 6][idx & 63] = W2[idx];
  __syncthreads();

  {
    int r = t >> 2, n0 = (t & 3) * 16;
    float acc[16];
    for (int j = 0; j < 16; ++j) acc[j] = b2[n0 + j];
    for (int k = 0; k < 64; ++k) {
      float f = s_h[r][k];
      for (int j = 0; j < 16; ++j) acc[j] += f * s_w[k][n0 + j];
    }
    __syncthreads();
    for (int j = 0; j < 16; ++j) s_feat[r][n0 + j] = fmaxf(acc[j], 0.0f);
  }
  __syncthreads();

  for (int h = 0; h < 2; ++h) {
    for (int idx = t; idx < 64 * 64; idx += 256)
      s_w[idx >> 6][idx & 63] = W3[(size_t)(idx >> 6) * 128 + h * 64 + (idx & 63)];
    __syncthreads();
    int n = t & 63, rg = t >> 6;
    float acc[16];
    float bias = b3[h * 64 + n];
    for (int rr = 0; rr < 16; ++rr) acc[rr] = bias;
    for (int k = 0; k < 64; ++k) {
      float w = s_w[k][n];
      for (int rr = 0; rr < 16; ++rr) acc[rr] += s_feat[rg * 16 + rr][k] * w;
    }
    float m = -__builtin_inff();
    for (int rr = 0; rr < 16; ++rr)
      m = fmaxf(m, fmaxf(acc[rr], 0.0f) + s_mask[rg * 16 + rr]);
    s_red[rg][n] = m;
    __syncthreads();
    if (t < 64) {
      float mm = fmaxf(fmaxf(s_red[0][t], s_red[1][t]), fmaxf(s_red[2][t], s_red[3][t]));
      out[(size_t)c * 128 + h * 64 + t] = mm;
    }
    __syncthreads();
  }
}

// ---------------------------------------------------------------------------
extern "C" void kernel_launch(void* const* d_in, const int* in_sizes, int n_in,
                              void* d_out, int out_size, void* d_ws, size_t ws_size,
                              hipStream_t stream) {
  const float* x   = (const float*)d_in[0];
  const float* pos = (const float*)d_in[1];
  // d_in[2] = batch (int32), unused
  const float* W1 = (const float*)d_in[3];
  const float* b1 = (const float*)d_in[4];
  const float* W2 = (const float*)d_in[5];
  const float* b2 = (const float*)d_in[6];
  const float* W3 = (const float*)d_in[7];
  const float* b3 = (const float*)d_in[8];

  float* out = (float*)d_out;
  int* samp = (int*)d_ws;                      // [8192]
  int* nbr = samp + BCL * MS;                  // [8192*64]
  float4* pts = (float4*)((int*)d_ws + WS_PTS_OFF);  // [4*8192] float4 (512 KB)

  sort_kernel<<<BCL, 1024, NPB * sizeof(u64), stream>>>(pos, pts);
  fps_loop_kernel<<<BCL, 64, 0, stream>>>(pos, pts, samp, out);
  nbr_kernel<<<BCL * MS, 256, 0, stream>>>(pos, samp, nbr);
  mlp_kernel<<<BCL * MS, 256, 0, stream>>>(x, pos, samp, nbr,
                                           W1, b1, W2, b2, W3, b3, out);
}

// Round 11
// 2098.473 us; speedup vs baseline: 9.9865x; 9.9865x over previous
//
#include <hip/hip_runtime.h>

typedef unsigned int u32;
typedef unsigned long long u64;
typedef float f32x2 __attribute__((ext_vector_type(2)));

#define NPB 8192
#define BCL 4
#define MS 2048
#define KN 64
#define OFF_POS   (BCL * MS * 128)            // element offsets into d_out (f32)
#define OFF_BATCH (OFF_POS + BCL * MS * 3)

__device__ inline u64 umax64(u64 a, u64 b) { return a < b ? b : a; }
__device__ inline u32 umax32(u32 a, u32 b) { return a < b ? b : a; }

// packed f32 ops: IEEE-identical per half to v_add_f32 / v_mul_f32 -> bit-exact
__device__ inline f32x2 pk_add(f32x2 a, f32x2 b) {
  f32x2 d;
  asm("v_pk_add_f32 %0, %1, %2" : "=v"(d) : "v"(a), "v"(b));
  return d;
}
__device__ inline f32x2 pk_mul(f32x2 a, f32x2 b) {
  f32x2 d;
  asm("v_pk_mul_f32 %0, %1, %2" : "=v"(d) : "v"(a), "v"(b));
  return d;
}

// wave64 max via DPP (VALU forwarding, no LDS round-trips).
__device__ inline u32 wave_max_u32(u32 v) {
  v = umax32(v, (u32)__builtin_amdgcn_update_dpp(0, (int)v, 0x111, 0xf, 0xf, false));
  v = umax32(v, (u32)__builtin_amdgcn_update_dpp(0, (int)v, 0x112, 0xf, 0xf, false));
  v = umax32(v, (u32)__builtin_amdgcn_update_dpp(0, (int)v, 0x114, 0xf, 0xf, false));
  v = umax32(v, (u32)__builtin_amdgcn_update_dpp(0, (int)v, 0x118, 0xf, 0xf, false));
  v = umax32(v, (u32)__builtin_amdgcn_update_dpp(0, (int)v, 0x142, 0xa, 0xf, false));
  v = umax32(v, (u32)__builtin_amdgcn_update_dpp(0, (int)v, 0x143, 0xc, 0xf, false));
  return (u32)__builtin_amdgcn_readlane((int)v, 63);
}
// two-phase DPP reduce == lexicographic u64 max over the wave (tie -> min idx)
__device__ inline u64 wave_max_key(u64 lkey) {
  u32 hi = (u32)(lkey >> 32), lo32v = (u32)lkey;
  u32 m = wave_max_u32(hi);
  u32 c = wave_max_u32(hi == m ? lo32v : 0u);
  return ((u64)m << 32) | c;
}

__device__ inline u32 part1by2(u32 x) {   // spread 10 bits -> every 3rd bit
  x &= 0x3ffu;
  x = (x | (x << 16)) & 0x030000FFu;
  x = (x | (x << 8))  & 0x0300F00Fu;
  x = (x | (x << 4))  & 0x030C30C3u;
  x = (x | (x << 2))  & 0x09249249u;
  return x;
}

// ---------------------------------------------------------------------------
// Kernel 1: FPS = R7 structure (1024 thr, 8 Morton-contiguous pts/thread in
// registers, bbox prune, DPP wave argmax) with R5's block combine: a single
// triple-buffered LDS atomicMax slot (fire-and-forget, off the VALU issue
// path) + ONE broadcast ds_read_b64, replacing the 16-slot scan (~55 instr/
// wave/iter of issue pressure). Every component proven bit-exact (absmax 0.0
// in R5/R6/R7). Key = d2bits<<32 | ~origidx -> np.argmax tie semantics.
// ---------------------------------------------------------------------------
__global__ __launch_bounds__(1024) void fps_kernel(
    const float* __restrict__ pos, int* __restrict__ samp,
    float* __restrict__ out) {
  extern __shared__ u64 smem[];   // 64 KB sort buffer; then slot[3] + s_samp
  int b = blockIdx.x, t = threadIdx.x, lane = t & 63;
  const float* pb = pos + (size_t)b * NPB * 3;

  // ---- 1) Morton keys (30b) | orig idx (13b) ----
  for (int i = t; i < NPB; i += 1024) {
    float xx = pb[i * 3], yy = pb[i * 3 + 1], zz = pb[i * 3 + 2];
    u32 xi = (u32)fminf(fmaxf(xx * 1024.0f, 0.0f), 1023.0f);
    u32 yi = (u32)fminf(fmaxf(yy * 1024.0f, 0.0f), 1023.0f);
    u32 zi = (u32)fminf(fmaxf(zz * 1024.0f, 0.0f), 1023.0f);
    u32 m = (part1by2(zi) << 2) | (part1by2(yi) << 1) | part1by2(xi);
    smem[i] = ((u64)m << 13) | (u32)i;
  }
  // ---- 2) bitonic sort 8192 ----
  for (int k = 2; k <= NPB; k <<= 1) {
    for (int j = k >> 1; j > 0; j >>= 1) {
      __syncthreads();
      for (int i = t; i < NPB; i += 1024) {
        int ix = i ^ j;
        if (ix > i) {
          u64 a = smem[i], c = smem[ix];
          bool up = ((i & k) == 0);
          if ((a > c) == up) { smem[i] = c; smem[ix] = a; }
        }
      }
    }
  }
  __syncthreads();
  // ---- 3) extract my 8-pt blob (Morton-contiguous) ----
  int oi[8];
  #pragma unroll
  for (int i = 0; i < 8; ++i) oi[i] = (int)(smem[8 * t + i] & 0x1FFFu);
  __syncthreads();                 // sort buffer dead; smem reused below

  u64* slot = smem;                // [3] triple-buffered atomicMax slots
  int* s_samp = (int*)(smem + 8);  // 2048 ints

  // ---- 4) gather coords + bbox + tie-break lo words; init vs point 0 ----
  f32x2 px[4], py[4], pz[4], mind[4];
  u32 lo[8];
  float bxl = 1e30f, bxh = -1e30f, byl = 1e30f, byh = -1e30f, bzl = 1e30f, bzh = -1e30f;
  #pragma unroll
  for (int j = 0; j < 4; ++j) {
    int iA = oi[2 * j], iB = oi[2 * j + 1];
    float xA = pb[iA * 3], yA = pb[iA * 3 + 1], zA = pb[iA * 3 + 2];
    float xB = pb[iB * 3], yB = pb[iB * 3 + 1], zB = pb[iB * 3 + 2];
    px[j] = f32x2{xA, xB}; py[j] = f32x2{yA, yB}; pz[j] = f32x2{zA, zB};
    lo[2 * j] = ~(u32)iA; lo[2 * j + 1] = ~(u32)iB;
    bxl = fminf(bxl, fminf(xA, xB)); bxh = fmaxf(bxh, fmaxf(xA, xB));
    byl = fminf(byl, fminf(yA, yB)); byh = fmaxf(byh, fmaxf(yA, yB));
    bzl = fminf(bzl, fminf(zA, zB)); bzh = fmaxf(bzh, fmaxf(zA, zB));
  }
  u64 lkey = 0, wkey;
  {
    float cx = pb[0], cy = pb[1], cz = pb[2];
    f32x2 mcx = f32x2{-cx, -cx}, mcy = f32x2{-cy, -cy}, mcz = f32x2{-cz, -cz};
    #pragma unroll
    for (int j = 0; j < 4; ++j) {
      f32x2 dx = pk_add(px[j], mcx), dy = pk_add(py[j], mcy), dz = pk_add(pz[j], mcz);
      mind[j] = pk_add(pk_add(pk_mul(dx, dx), pk_mul(dy, dy)), pk_mul(dz, dz));
      u64 kA = ((u64)__float_as_uint(mind[j].x) << 32) | lo[2 * j];
      u64 kB = ((u64)__float_as_uint(mind[j].y) << 32) | lo[2 * j + 1];
      lkey = umax64(lkey, umax64(kA, kB));
    }
    wkey = wave_max_key(lkey);
  }
  if (t < 3) slot[t] = 0;
  if (t == 0) s_samp[0] = 0;
  __syncthreads();                 // slots zeroed before first atomicMax

  // ---- 5) sequential loop: ONE barrier/iter, R5-proven slot rotation ----
  int cur = 0, nxt = 1;
  for (int it = 1; it < MS; ++it) {
    if (lane == 0) atomicMax((u64*)&slot[cur], wkey);
    if (t == 0) slot[nxt] = 0;     // zeroes cur_{it+1}; 2 barriers before reuse
    __syncthreads();
    u64 g = slot[cur];             // broadcast read (same addr, no conflict)
    int win = (int)(~(u32)g) & (NPB - 1);
    if (t == 0) s_samp[it] = win;
    // winner coords: uniform load, L2-resident 96 KB cloud
    float ncx = pb[win * 3], ncy = pb[win * 3 + 1], ncz = pb[win * 3 + 2];
    // conservative bbox skip test (bit-exact: only skips provable no-ops)
    float lmax = __uint_as_float((u32)(lkey >> 32));
    float ax = fmaxf(fmaxf(__fsub_rn(bxl, ncx), __fsub_rn(ncx, bxh)), 0.0f);
    float ay = fmaxf(fmaxf(__fsub_rn(byl, ncy), __fsub_rn(ncy, byh)), 0.0f);
    float az = fmaxf(fmaxf(__fsub_rn(bzl, ncz), __fsub_rn(ncz, bzh)), 0.0f);
    float lb2 = (ax * ax + ay * ay + az * az) * 0.9999961853f;  // *(1-2^-18)
    bool upd = (lb2 <= lmax);
    if (__ballot(upd)) {           // wave-uniform branch
      if (upd) {
        f32x2 mcx = f32x2{-ncx, -ncx}, mcy = f32x2{-ncy, -ncy}, mcz = f32x2{-ncz, -ncz};
        u64 acc = 0;
        #pragma unroll
        for (int j = 0; j < 4; ++j) {
          f32x2 dx = pk_add(px[j], mcx), dy = pk_add(py[j], mcy), dz = pk_add(pz[j], mcz);
          f32x2 d2 = pk_add(pk_add(pk_mul(dx, dx), pk_mul(dy, dy)), pk_mul(dz, dz));
          mind[j].x = fminf(mind[j].x, d2.x);
          mind[j].y = fminf(mind[j].y, d2.y);
          u64 kA = ((u64)__float_as_uint(mind[j].x) << 32) | lo[2 * j];
          u64 kB = ((u64)__float_as_uint(mind[j].y) << 32) | lo[2 * j + 1];
          acc = umax64(acc, umax64(kA, kB));
        }
        lkey = acc;
      }
      wkey = wave_max_key(lkey);   // all lanes participate (DPP)
    }
    cur = nxt;
    nxt = nxt + 1 == 3 ? 0 : nxt + 1;
  }
  __syncthreads();
  // ---- 6) writeback ----
  float* pos_out = out + OFF_POS + (size_t)b * MS * 3;
  float* batch_out = out + OFF_BATCH + (size_t)b * MS;
  for (int m = t; m < MS; m += 1024) {
    int s = s_samp[m];
    samp[b * MS + m] = s;
    pos_out[m * 3] = pb[s * 3];
    pos_out[m * 3 + 1] = pb[s * 3 + 1];
    pos_out[m * 3 + 2] = pb[s * 3 + 2];
    batch_out[m] = (float)b;
  }
}

// ---------------------------------------------------------------------------
// Kernel 2: radius ball + K-nearest-in-ball (lax.top_k semantics). FROZEN.
// ---------------------------------------------------------------------------
__global__ __launch_bounds__(256) void nbr_kernel(
    const float* __restrict__ pos, const int* __restrict__ samp,
    int* __restrict__ nbr) {
  const float R2CUT = (float)(0.2 * 0.2);   // 0x3D23D70A
  int c = blockIdx.x, b = c >> 11, t = threadIdx.x;
  const float* pb = pos + (size_t)b * NPB * 3;
  int s = samp[c] & (NPB - 1);
  float cx = pb[s * 3], cy = pb[s * 3 + 1], cz = pb[s * 3 + 2];
  __shared__ u64 cand[512];
  __shared__ int cnt;
  if (t == 0) cnt = 0;
  __syncthreads();
  for (int j = t; j < NPB; j += 256) {
    float dx = __fsub_rn(pb[j * 3], cx);
    float dy = __fsub_rn(pb[j * 3 + 1], cy);
    float dz = __fsub_rn(pb[j * 3 + 2], cz);
    float d2 = __fadd_rn(__fadd_rn(__fmul_rn(dx, dx), __fmul_rn(dy, dy)), __fmul_rn(dz, dz));
    if (d2 <= R2CUT) {
      int sl = atomicAdd(&cnt, 1);
      if (sl < 512) cand[sl] = ((u64)__float_as_uint(d2) << 32) | (u32)j;
    }
  }
  __syncthreads();
  int n = cnt; if (n > 512) n = 512;
  for (int i = t; i < 512; i += 256) if (i >= n) cand[i] = ~0ull;
  __syncthreads();
  for (int k = 2; k <= 512; k <<= 1) {
    for (int j = k >> 1; j > 0; j >>= 1) {
      for (int i = t; i < 512; i += 256) {
        int ix = i ^ j;
        if (ix > i) {
          u64 a = cand[i], bb = cand[ix];
          bool up = ((i & k) == 0);
          if ((a > bb) == up) { cand[i] = bb; cand[ix] = a; }
        }
      }
      __syncthreads();
    }
  }
  if (t < KN) nbr[(size_t)c * KN + t] = (t < n) ? (int)(cand[t] & 0xffffffffu) : -1;
}

// ---------------------------------------------------------------------------
// Kernel 3: gather -> f32 VALU MLP -> masked max-pool. FROZEN (absmax 0.0).
// ---------------------------------------------------------------------------
__global__ __launch_bounds__(256) void mlp_kernel(
    const float* __restrict__ x, const float* __restrict__ pos,
    const int* __restrict__ samp, const int* __restrict__ nbr,
    const float* __restrict__ W1, const float* __restrict__ b1,
    const float* __restrict__ W2, const float* __restrict__ b2,
    const float* __restrict__ W3, const float* __restrict__ b3,
    float* __restrict__ out) {
  int c = blockIdx.x, b = c >> 11, t = threadIdx.x;

  __shared__ float s_feat[64][68];
  __shared__ float s_h[64][68];
  __shared__ float s_w[68][64];
  __shared__ float s_mask[64];
  __shared__ float s_red[4][64];

  const int* nb = nbr + (size_t)c * KN;

  {
    int r = t >> 2, q = t & 3;
    int j = nb[r];
    bool valid = (j >= 0 && j < NPB);
    size_t jj = valid ? (size_t)j : 0;
    const float4* xp = (const float4*)(x + ((size_t)b * NPB + jj) * 64 + q * 16);
    float4 v[4];
    for (int i = 0; i < 4; ++i) v[i] = xp[i];
    for (int i = 0; i < 4; ++i) {
      s_feat[r][q * 16 + i * 4 + 0] = valid ? v[i].x : 0.0f;
      s_feat[r][q * 16 + i * 4 + 1] = valid ? v[i].y : 0.0f;
      s_feat[r][q * 16 + i * 4 + 2] = valid ? v[i].z : 0.0f;
      s_feat[r][q * 16 + i * 4 + 3] = valid ? v[i].w : 0.0f;
    }
  }
  if (t < 64) {
    int r = t;
    int j = nb[r];
    bool valid = (j >= 0 && j < NPB);
    s_mask[r] = valid ? 0.0f : -__builtin_inff();
    int s = samp[c] & (NPB - 1);
    size_t jj = valid ? (size_t)j : (size_t)s;
    for (int d = 0; d < 3; ++d) {
      float pj = pos[((size_t)b * NPB + jj) * 3 + d];
      float pc = pos[((size_t)b * NPB + s) * 3 + d];
      s_feat[r][64 + d] = __fsub_rn(pj, pc);
    }
  }
  for (int idx = t; idx < 67 * 64; idx += 256)
    s_w[idx >> 6][idx & 63] = W1[idx];
  __syncthreads();

  {
    int r = t >> 2, n0 = (t & 3) * 16;
    float acc[16];
    for (int j = 0; j < 16; ++j) acc[j] = b1[n0 + j];
    for (int k = 0; k < 67; ++k) {
      float f = s_feat[r][k];
      for (int j = 0; j < 16; ++j) acc[j] += f * s_w[k][n0 + j];
    }
    __syncthreads();
    for (int j = 0; j < 16; ++j) s_h[r][n0 + j] = fmaxf(acc[j], 0.0f);
  }
  for (int idx = t; idx < 64 * 64; idx += 256)
    s_w[idx >> 6][idx & 63] = W2[idx];
  __syncthreads();

  {
    int r = t >> 2, n0 = (t & 3) * 16;
    float acc[16];
    for (int j = 0; j < 16; ++j) acc[j] = b2[n0 + j];
    for (int k = 0; k < 64; ++k) {
      float f = s_h[r][k];
      for (int j = 0; j < 16; ++j) acc[j] += f * s_w[k][n0 + j];
    }
    __syncthreads();
    for (int j = 0; j < 16; ++j) s_feat[r][n0 + j] = fmaxf(acc[j], 0.0f);
  }
  __syncthreads();

  for (int h = 0; h < 2; ++h) {
    for (int idx = t; idx < 64 * 64; idx += 256)
      s_w[idx >> 6][idx & 63] = W3[(size_t)(idx >> 6) * 128 + h * 64 + (idx & 63)];
    __syncthreads();
    int n = t & 63, rg = t >> 6;
    float acc[16];
    float bias = b3[h * 64 + n];
    for (int rr = 0; rr < 16; ++rr) acc[rr] = bias;
    for (int k = 0; k < 64; ++k) {
      float w = s_w[k][n];
      for (int rr = 0; rr < 16; ++rr) acc[rr] += s_feat[rg * 16 + rr][k] * w;
    }
    float m = -__builtin_inff();
    for (int rr = 0; rr < 16; ++rr)
      m = fmaxf(m, fmaxf(acc[rr], 0.0f) + s_mask[rg * 16 + rr]);
    s_red[rg][n] = m;
    __syncthreads();
    if (t < 64) {
      float mm = fmaxf(fmaxf(s_red[0][t], s_red[1][t]), fmaxf(s_red[2][t], s_red[3][t]));
      out[(size_t)c * 128 + h * 64 + t] = mm;
    }
    __syncthreads();
  }
}

// ---------------------------------------------------------------------------
extern "C" void kernel_launch(void* const* d_in, const int* in_sizes, int n_in,
                              void* d_out, int out_size, void* d_ws, size_t ws_size,
                              hipStream_t stream) {
  const float* x   = (const float*)d_in[0];
  const float* pos = (const float*)d_in[1];
  // d_in[2] = batch (int32), unused
  const float* W1 = (const float*)d_in[3];
  const float* b1 = (const float*)d_in[4];
  const float* W2 = (const float*)d_in[5];
  const float* b2 = (const float*)d_in[6];
  const float* W3 = (const float*)d_in[7];
  const float* b3 = (const float*)d_in[8];

  float* out = (float*)d_out;
  int* samp = (int*)d_ws;            // [8192]
  int* nbr = samp + BCL * MS;        // [8192*64]

  fps_kernel<<<BCL, 1024, NPB * sizeof(u64), stream>>>(pos, samp, out);
  nbr_kernel<<<BCL * MS, 256, 0, stream>>>(pos, samp, nbr);
  mlp_kernel<<<BCL * MS, 256, 0, stream>>>(x, pos, samp, nbr,
                                           W1, b1, W2, b2, W3, b3, out);
}